// Round 19
// baseline (182.327 us; speedup 1.0000x reference)
//
#include <hip/hip_runtime.h>
#include <hip/hip_bf16.h>

typedef unsigned short u16;
typedef unsigned int u32;
using bf16x8 = __attribute__((ext_vector_type(8))) short;
using f32x4  = __attribute__((ext_vector_type(4))) float;

#define LDA   136   // 128 + 8 pad
#define SLOTS 16
#define NROWS 96    // SLOTS * 6

__device__ __forceinline__ u32 pk2bf(float a, float b) {
  u32 r;
  asm("v_cvt_pk_bf16_f32 %0, %1, %2" : "=v"(r) : "v"(a), "v"(b));
  return r;
}
__device__ __forceinline__ u16 f2bf(float f) { return (u16)pk2bf(f, f); }
__device__ __forceinline__ float bf2f(u16 h) {
  union { u32 u; float f; } v; v.u = ((u32)h) << 16;
  return v.f;
}
__device__ __forceinline__ float2 bf2x2(u32 u) {
  union { u32 u; float f; } a, b; a.u = u << 16; b.u = u & 0xffff0000u;
  return make_float2(a.f, b.f);
}

#if __has_builtin(__builtin_amdgcn_exp2f)
#define EXP2F(x) __builtin_amdgcn_exp2f(x)
#else
#define EXP2F(x) exp2f(x)
#endif

#define MFMA32(a, b, c) __builtin_amdgcn_mfma_f32_16x16x32_bf16(a, b, c, 0, 0, 0)

// tanh-form GELU (validated R3-R18: absmax stays 0.0625)
__device__ __forceinline__ float gelu_f(float x) {
  const float a = x * x;
  const float b = fmaf(-0.10294538f, a, -2.3022077f);
  const float e = EXP2F(x * b);
  return x * __builtin_amdgcn_rcpf(1.f + e);
}

// ---------------- weight convert + transpose to bf16 ----------------
// ws layout (u16): qwT[128*128] kwT vwT owT | ff1T[512*128] | ff2T[128*512]
__global__ void convert_w(const float* __restrict__ qw, const float* __restrict__ kw,
                          const float* __restrict__ vw, const float* __restrict__ ow,
                          const float* __restrict__ f1, const float* __restrict__ f2,
                          u16* __restrict__ o) {
  int i = blockIdx.x * 256 + threadIdx.x;
  if (i < 65536) {
    int which = i >> 14;
    const float* W = which == 0 ? qw : which == 1 ? kw : which == 2 ? vw : ow;
    int t = i & 16383;
    int n = t >> 7, k = t & 127;
    o[i] = f2bf(W[k * 128 + n]);
  } else if (i < 131072) {
    int t = i - 65536;
    int n = t >> 7, k = t & 127;
    o[i] = f2bf(f1[k * 512 + n]);
  } else if (i < 196608) {
    int t = i - 131072;
    int n = t >> 9, k = t & 511;
    o[i] = f2bf(f2[k * 128 + n]);
  }
}

// 96-row 8-wave GEMM: wave owns ONE 16-col tile (col0 = wave*16), 6 row-tiles.
// Weight reads partitioned 1:1 across waves (R17 lesson: never duplicate).
// mfma(F1,F2): lane(l16,kg) holds D[f2row=l16][f1row=kg*4+r]; acc[6] = 24 VGPRs.
__device__ __forceinline__ void gemm96(const u16* __restrict__ A, const u16* __restrict__ WT,
                                       int ldw, f32x4 acc[6],
                                       int wave, int lane16, int kgrp) {
#pragma unroll
  for (int ks = 0; ks < 4; ++ks) {
    const int kk = ks * 32 + kgrp * 8;
    const bf16x8 b = *(const bf16x8*)(WT + (wave * 16 + lane16) * ldw + kk);
    __builtin_amdgcn_s_setprio(1);
#pragma unroll
    for (int xr = 0; xr < 6; ++xr) {
      const bf16x8 a = *(const bf16x8*)(A + (xr * 16 + lane16) * LDA + kk);
      acc[xr] = MFMA32(b, a, acc[xr]);
    }
    __builtin_amdgcn_s_setprio(0);
  }
}

// Fused Q||K GEMM: A-fragments read ONCE (half the LDS A-traffic of two calls),
// two exclusive weight streams in flight, 12 interleaved MFMAs/ks.
// All 48 acc regs are phase-local (both stores precede the barrier).
__device__ __forceinline__ void gemm96_qk(const u16* __restrict__ A,
                                          const u16* __restrict__ WTq,
                                          const u16* __restrict__ WTk,
                                          f32x4 aq[6], f32x4 ak[6],
                                          int wave, int lane16, int kgrp) {
#pragma unroll
  for (int ks = 0; ks < 4; ++ks) {
    const int kk = ks * 32 + kgrp * 8;
    const int r = (wave * 16 + lane16) * 128 + kk;
    const bf16x8 bq = *(const bf16x8*)(WTq + r);
    const bf16x8 bk = *(const bf16x8*)(WTk + r);
    __builtin_amdgcn_s_setprio(1);
#pragma unroll
    for (int xr = 0; xr < 6; ++xr) {
      const bf16x8 a = *(const bf16x8*)(A + (xr * 16 + lane16) * LDA + kk);
      aq[xr] = MFMA32(bq, a, aq[xr]);
      ak[xr] = MFMA32(bk, a, ak[xr]);
    }
    __builtin_amdgcn_s_setprio(0);
  }
}

__device__ __forceinline__ void store96(u16* __restrict__ dst, f32x4 acc[6],
                                        const float* __restrict__ bias,
                                        int wave, int lane16, int kgrp) {
  const int col0 = wave * 16 + kgrp * 4;
  const float4 bv = *(const float4*)(bias + col0);
#pragma unroll
  for (int xr = 0; xr < 6; ++xr) {
    uint2 o;
    o.x = pk2bf(acc[xr][0] + bv.x, acc[xr][1] + bv.y);
    o.y = pk2bf(acc[xr][2] + bv.z, acc[xr][3] + bv.w);
    *(uint2*)(dst + (xr * 16 + lane16) * LDA + col0) = o;
  }
}

// min 4 waves/EU (we are LDS-capped at 2 blocks/CU = 4 waves/SIMD anyway)
// -> allows up to 128 VGPRs so the QK fusion's 48 phase-local accs don't spill.
__global__ __launch_bounds__(512, 4) void mitra_main(
    const float* __restrict__ x,
    const float* __restrict__ nw1, const float* __restrict__ nb1,
    const float* __restrict__ nw2, const float* __restrict__ nb2,
    const float* __restrict__ qb,  const float* __restrict__ kb,
    const float* __restrict__ vb,  const float* __restrict__ ob,
    const float* __restrict__ f1b, const float* __restrict__ f2b,
    const u16* __restrict__ wt, float* __restrict__ out) {
  __shared__ u16 XF[NROWS * LDA];   // xf -> xf2 -> FF G ping buffer
  __shared__ u16 BA[NROWS * LDA];   // Q -> V -> H
  __shared__ u16 BB[NROWS * LDA];   // K -> O -> FF G pong buffer
  __shared__ u16 PS2[2 * NROWS * 8];   // scores/probs bf16: [h][q][k-in-slot(6, pad 8)]

  const int tid    = threadIdx.x;
  const int wave   = tid >> 6;      // 0..7
  const int lane   = tid & 63;
  const int lane16 = lane & 15;
  const int kgrp   = lane >> 4;
  const long slot0 = (long)blockIdx.x * SLOTS;

  // ---------- Phase 0: LN1(768) + LN2(128) -> XF  (wave handles 2 slots) ----------
#pragma unroll
  for (int si = 0; si < 2; ++si) {
    const int s = wave + si * 8;      // slot 0..15
    const float* xr = x + (size_t)(slot0 + s) * 768;
    const int l32 = lane & 31;
    float4 v[3];
    float sm = 0.f, sq = 0.f;
#pragma unroll
    for (int p = 0; p < 3; ++p) {
      v[p] = *(const float4*)(xr + (p * 64 + lane) * 4);
      sm += v[p].x + v[p].y + v[p].z + v[p].w;
      sq += v[p].x * v[p].x + v[p].y * v[p].y + v[p].z * v[p].z + v[p].w * v[p].w;
    }
#pragma unroll
    for (int m = 1; m < 64; m <<= 1) { sm += __shfl_xor(sm, m); sq += __shfl_xor(sq, m); }
    const float mu = sm * (1.f / 768.f);
    const float rs = rsqrtf(sq * (1.f / 768.f) - mu * mu + 1e-5f);
#pragma unroll
    for (int p = 0; p < 3; ++p) {
      const float4 w = *(const float4*)(nw1 + (p * 64 + lane) * 4);
      const float4 b = *(const float4*)(nb1 + (p * 64 + lane) * 4);
      v[p].x = (v[p].x - mu) * rs * w.x + b.x;
      v[p].y = (v[p].y - mu) * rs * w.y + b.y;
      v[p].z = (v[p].z - mu) * rs * w.z + b.z;
      v[p].w = (v[p].w - mu) * rs * w.w + b.w;
    }
    const float4 w2 = *(const float4*)(nw2 + l32 * 4);
    const float4 b2 = *(const float4*)(nb2 + l32 * 4);
#pragma unroll
    for (int p = 0; p < 3; ++p) {
      float s2 = v[p].x + v[p].y + v[p].z + v[p].w;
      float q2 = v[p].x * v[p].x + v[p].y * v[p].y + v[p].z * v[p].z + v[p].w * v[p].w;
#pragma unroll
      for (int m = 1; m < 32; m <<= 1) { s2 += __shfl_xor(s2, m); q2 += __shfl_xor(q2, m); }
      const float mu2 = s2 * (1.f / 128.f);
      const float rs2 = rsqrtf(q2 * (1.f / 128.f) - mu2 * mu2 + 1e-5f);
      const int row = s * 6 + 2 * p + (lane >> 5);
      uint2 o;
      o.x = pk2bf((v[p].x - mu2) * rs2 * w2.x + b2.x, (v[p].y - mu2) * rs2 * w2.y + b2.y);
      o.y = pk2bf((v[p].z - mu2) * rs2 * w2.z + b2.z, (v[p].w - mu2) * rs2 * w2.w + b2.w);
      *(uint2*)(XF + row * LDA + l32 * 4) = o;
    }
  }
  __syncthreads();

  // ---------- Q -> BA, K -> BB (fused: one A-pass, two B-streams) ----------
  {
    f32x4 aq[6] = {}, ak[6] = {};
    gemm96_qk(XF, wt, wt + 16384, aq, ak, wave, lane16, kgrp);
    store96(BA, aq, qb, wave, lane16, kgrp);
    store96(BB, ak, kb, wave, lane16, kgrp);
  }
  __syncthreads();

  // ---------- scores via MFMA: 28 jobs (14 near-diag tiles x 2 heads) over 8 waves ----------
  {
#pragma unroll
    for (int jl = 0; jl < 4; ++jl) {
      const int j = wave + jl * 8;
      if (j < 28) {
        const int h  = j & 1;
        const int tt = j >> 1;                 // 0..13
        int qt, kt;
        if (tt < 6) { qt = tt; kt = tt; }
        else {
          const int idx  = tt - 6;             // 0..7
          const int base = idx >> 1;           // 0..3
          const int lo   = base + (base >> 1); // 0,1,3,4
          const int dir  = idx & 1;
          qt = lo + dir; kt = lo + 1 - dir;
        }
        f32x4 acc = {};
#pragma unroll
        for (int ks = 0; ks < 2; ++ks) {
          const int kk = h * 64 + ks * 32 + kgrp * 8;
          const bf16x8 kf = *(const bf16x8*)(BB + (kt * 16 + lane16) * LDA + kk);
          const bf16x8 qf = *(const bf16x8*)(BA + (qt * 16 + lane16) * LDA + kk);
          acc = MFMA32(kf, qf, acc);
        }
        const int q    = qt * 16 + lane16;
        const int klo  = 6 * ((unsigned)q / 6u);
        u16* pq = PS2 + (h * NROWS + q) * 8;
#pragma unroll
        for (int r = 0; r < 4; ++r) {
          const int off = kt * 16 + kgrp * 4 + r - klo;
          if ((unsigned)off < 6u) pq[off] = f2bf(acc[r] * 0.125f);
        }
      }
    }
  }
  __syncthreads();

  // ---------- V -> BA (Q dead) with softmax merged (PS2-only, no hazard) ----------
  {
    f32x4 acc[6] = {};
    gemm96(XF, wt + 32768, 128, acc, wave, lane16, kgrp);
    store96(BA, acc, vb, wave, lane16, kgrp);
  }
  if (lane < 24) {
    const int h  = lane / 12;
    const int q  = wave * 12 + (lane % 12);
    u16* pr = PS2 + (h * NROWS + q) * 8;
    float e[6];
    float m = bf2f(pr[0]);
#pragma unroll
    for (int k = 1; k < 6; ++k) m = fmaxf(m, bf2f(pr[k]));
    float ssum = 0.f;
#pragma unroll
    for (int k = 0; k < 6; ++k) { e[k] = EXP2F((bf2f(pr[k]) - m) * 1.44269504f); ssum += e[k]; }
    const float inv = __builtin_amdgcn_rcpf(ssum);
#pragma unroll
    for (int k = 0; k < 6; ++k) pr[k] = f2bf(e[k] * inv);
  }
  __syncthreads();

  // ---------- O = P @ V -> BB: wave w owns rows 12w..12w+11, all 128 cols ----------
  {
    const int dseg = lane & 15;
    const int d0   = dseg * 8;
    const int h    = dseg >> 3;
    const int rgrp = lane >> 4;
#pragma unroll
    for (int p = 0; p < 3; ++p) {
      const int rl = rgrp * 3 + p;          // 0..11
      const int q  = wave * 12 + rl;
      const int sl = rl / 6;
      const u16* pr = PS2 + (h * NROWS + q) * 8;
      const u16* vbase = BA + (wave * 12 + sl * 6) * LDA + d0;
      float o0 = 0, o1 = 0, o2 = 0, o3 = 0, o4 = 0, o5 = 0, o6 = 0, o7 = 0;
#pragma unroll
      for (int k = 0; k < 6; ++k) {
        const uint4 v4 = *(const uint4*)(vbase + k * LDA);
        const float pw = bf2f(pr[k]);
        const float2 a = bf2x2(v4.x), b = bf2x2(v4.y);
        const float2 c = bf2x2(v4.z), d = bf2x2(v4.w);
        o0 = fmaf(pw, a.x, o0); o1 = fmaf(pw, a.y, o1);
        o2 = fmaf(pw, b.x, o2); o3 = fmaf(pw, b.y, o3);
        o4 = fmaf(pw, c.x, o4); o5 = fmaf(pw, c.y, o5);
        o6 = fmaf(pw, d.x, o6); o7 = fmaf(pw, d.y, o7);
      }
      uint4 o;
      o.x = pk2bf(o0, o1); o.y = pk2bf(o2, o3);
      o.z = pk2bf(o4, o5); o.w = pk2bf(o6, o7);
      *(uint4*)(BB + q * LDA + d0) = o;
    }
  }
  __syncthreads();

  // ---------- att_out = O @ ow + ob ; xf2 = xf + att_out -> XF ----------
  {
    f32x4 acc[6] = {};
    gemm96(BB, wt + 49152, 128, acc, wave, lane16, kgrp);
    const int col0 = wave * 16 + kgrp * 4;
    const float4 bv = *(const float4*)(ob + col0);
#pragma unroll
    for (int xr = 0; xr < 6; ++xr) {
      u16* px = XF + (xr * 16 + lane16) * LDA + col0;
      const uint2 cur = *(const uint2*)px;
      const float2 lo = bf2x2(cur.x), hi = bf2x2(cur.y);
      uint2 o;
      o.x = pk2bf(lo.x + acc[xr][0] + bv.x, lo.y + acc[xr][1] + bv.y);
      o.y = pk2bf(hi.x + acc[xr][2] + bv.z, hi.y + acc[xr][3] + bv.w);
      *(uint2*)px = o;
    }
  }
  __syncthreads();

  // ---------- H = LN2(xf2) -> BA (V dead): 16 groups x 6 rows ----------
  {
    const int g = tid >> 5, l32 = tid & 31;
    const float4 w2 = *(const float4*)(nw2 + l32 * 4);
    const float4 b2 = *(const float4*)(nb2 + l32 * 4);
#pragma unroll
    for (int i = 0; i < 6; ++i) {
      const int row = g * 6 + i;
      const uint2 hv = *(const uint2*)(XF + row * LDA + l32 * 4);
      const float2 lo = bf2x2(hv.x), hi = bf2x2(hv.y);
      float s2 = lo.x + lo.y + hi.x + hi.y;
      float q2 = lo.x * lo.x + lo.y * lo.y + hi.x * hi.x + hi.y * hi.y;
#pragma unroll
      for (int m = 1; m < 32; m <<= 1) { s2 += __shfl_xor(s2, m); q2 += __shfl_xor(q2, m); }
      const float mu2 = s2 * (1.f / 128.f);
      const float rs2 = rsqrtf(q2 * (1.f / 128.f) - mu2 * mu2 + 1e-5f);
      uint2 o;
      o.x = pk2bf((lo.x - mu2) * rs2 * w2.x + b2.x, (lo.y - mu2) * rs2 * w2.y + b2.y);
      o.y = pk2bf((hi.x - mu2) * rs2 * w2.z + b2.z, (hi.y - mu2) * rs2 * w2.w + b2.w);
      *(uint2*)(BA + row * LDA + l32 * 4) = o;
    }
  }

  // ---------- preload acc2 with xf2 (frees XF as an FF G buffer) ----------
  f32x4 acc2[6];
  {
    const int col0 = wave * 16 + kgrp * 4;
#pragma unroll
    for (int xr = 0; xr < 6; ++xr) {
      const uint2 t2 = *(const uint2*)(XF + (xr * 16 + lane16) * LDA + col0);
      const float2 lo = bf2x2(t2.x), hi = bf2x2(t2.y);
      acc2[xr][0] = lo.x; acc2[xr][1] = lo.y;
      acc2[xr][2] = hi.x; acc2[xr][3] = hi.y;
    }
  }
  __syncthreads();

  // ---------- FF with G ping-pong {BB, XF}: one barrier per t ----------
  {
    f32x4 g[6] = {};
    gemm96(BA, wt + 65536, 128, g, wave, lane16, kgrp);
    const int col0 = wave * 16 + kgrp * 4;
    const float4 bv = *(const float4*)(f1b + col0);
#pragma unroll
    for (int xr = 0; xr < 6; ++xr) {
      uint2 o;
      o.x = pk2bf(gelu_f(g[xr][0] + bv.x), gelu_f(g[xr][1] + bv.y));
      o.y = pk2bf(gelu_f(g[xr][2] + bv.z), gelu_f(g[xr][3] + bv.w));
      *(uint2*)(BB + (xr * 16 + lane16) * LDA + col0) = o;
    }
  }
  __syncthreads();
#pragma unroll
  for (int t = 1; t < 4; ++t) {
    u16* const Gprev = (t & 1) ? BB : XF;
    u16* const Gcur  = (t & 1) ? XF : BB;
    gemm96(Gprev, wt + 131072 + (t - 1) * 128, 512, acc2, wave, lane16, kgrp);
    f32x4 g[6] = {};
    gemm96(BA, wt + 65536 + t * 16384, 128, g, wave, lane16, kgrp);
    const int col0 = wave * 16 + kgrp * 4;
    const float4 bv = *(const float4*)(f1b + t * 128 + col0);
#pragma unroll
    for (int xr = 0; xr < 6; ++xr) {
      uint2 o;
      o.x = pk2bf(gelu_f(g[xr][0] + bv.x), gelu_f(g[xr][1] + bv.y));
      o.y = pk2bf(gelu_f(g[xr][2] + bv.z), gelu_f(g[xr][3] + bv.w));
      *(uint2*)(Gcur + (xr * 16 + lane16) * LDA + col0) = o;
    }
    __syncthreads();
  }
  gemm96(XF, wt + 131072 + 3 * 128, 512, acc2, wave, lane16, kgrp);

  // ---------- out = x + (xf2 + ff_out) + ff2b  (acc2 already holds xf2) ----------
  {
    const int col0 = wave * 16 + kgrp * 4;
    const float4 fb = *(const float4*)(f2b + col0);
#pragma unroll
    for (int xr = 0; xr < 6; ++xr) {
      const int row  = xr * 16 + lane16;
      const int slot = row / 6, ch = row % 6;
      const size_t gi = (size_t)(slot0 + slot) * 768 + ch * 128 + col0;
      const float4 xv = *(const float4*)(x + gi);
      float4 o;
      o.x = xv.x + acc2[xr][0] + fb.x;
      o.y = xv.y + acc2[xr][1] + fb.y;
      o.z = xv.z + acc2[xr][2] + fb.z;
      o.w = xv.w + acc2[xr][3] + fb.w;
      *(float4*)(out + gi) = o;
    }
  }
}

extern "C" void kernel_launch(void* const* d_in, const int* in_sizes, int n_in,
                              void* d_out, int out_size, void* d_ws, size_t ws_size,
                              hipStream_t stream) {
  const float* x   = (const float*)d_in[0];
  const float* nw1 = (const float*)d_in[1];
  const float* nb1 = (const float*)d_in[2];
  const float* nw2 = (const float*)d_in[3];
  const float* nb2 = (const float*)d_in[4];
  const float* qw  = (const float*)d_in[5];
  const float* qb  = (const float*)d_in[6];
  const float* kw  = (const float*)d_in[7];
  const float* kb  = (const float*)d_in[8];
  const float* vw  = (const float*)d_in[9];
  const float* vb  = (const float*)d_in[10];
  const float* ow  = (const float*)d_in[11];
  const float* ob  = (const float*)d_in[12];
  const float* f1w = (const float*)d_in[13];
  const float* f1b = (const float*)d_in[14];
  const float* f2w = (const float*)d_in[15];
  const float* f2b = (const float*)d_in[16];
  u16* wt = (u16*)d_ws;   // 196608 u16 = 384 KB

  convert_w<<<768, 256, 0, stream>>>(qw, kw, vw, ow, f1w, f2w, wt);

  const int M = in_sizes[0] / 768;   // 32768 slots
  mitra_main<<<M / SLOTS, 512, 0, stream>>>(x, nw1, nb1, nw2, nb2,
                                            qb, kb, vb, ob, f1b, f2b,
                                            wt, (float*)d_out);
}

// Round 20
// 179.654 us; speedup vs baseline: 1.0149x; 1.0149x over previous
//
#include <hip/hip_runtime.h>
#include <hip/hip_bf16.h>

typedef unsigned short u16;
typedef unsigned int u32;
using bf16x8 = __attribute__((ext_vector_type(8))) short;
using f32x4  = __attribute__((ext_vector_type(4))) float;

#define LDA   136   // 128 + 8 pad
#define SLOTS 16
#define NROWS 96    // SLOTS * 6

__device__ __forceinline__ u32 pk2bf(float a, float b) {
  u32 r;
  asm("v_cvt_pk_bf16_f32 %0, %1, %2" : "=v"(r) : "v"(a), "v"(b));
  return r;
}
__device__ __forceinline__ u16 f2bf(float f) { return (u16)pk2bf(f, f); }
__device__ __forceinline__ float bf2f(u16 h) {
  union { u32 u; float f; } v; v.u = ((u32)h) << 16;
  return v.f;
}
__device__ __forceinline__ float2 bf2x2(u32 u) {
  union { u32 u; float f; } a, b; a.u = u << 16; b.u = u & 0xffff0000u;
  return make_float2(a.f, b.f);
}

#if __has_builtin(__builtin_amdgcn_exp2f)
#define EXP2F(x) __builtin_amdgcn_exp2f(x)
#else
#define EXP2F(x) exp2f(x)
#endif

#define MFMA32(a, b, c) __builtin_amdgcn_mfma_f32_16x16x32_bf16(a, b, c, 0, 0, 0)

// tanh-form GELU (validated R3-R19: absmax stays 0.0625)
__device__ __forceinline__ float gelu_f(float x) {
  const float a = x * x;
  const float b = fmaf(-0.10294538f, a, -2.3022077f);
  const float e = EXP2F(x * b);
  return x * __builtin_amdgcn_rcpf(1.f + e);
}

// ---------------- weight convert + transpose to bf16 ----------------
// ws layout (u16): qwT[128*128] kwT vwT owT | ff1T[512*128] | ff2T[128*512]
__global__ void convert_w(const float* __restrict__ qw, const float* __restrict__ kw,
                          const float* __restrict__ vw, const float* __restrict__ ow,
                          const float* __restrict__ f1, const float* __restrict__ f2,
                          u16* __restrict__ o) {
  int i = blockIdx.x * 256 + threadIdx.x;
  if (i < 65536) {
    int which = i >> 14;
    const float* W = which == 0 ? qw : which == 1 ? kw : which == 2 ? vw : ow;
    int t = i & 16383;
    int n = t >> 7, k = t & 127;
    o[i] = f2bf(W[k * 128 + n]);
  } else if (i < 131072) {
    int t = i - 65536;
    int n = t >> 7, k = t & 127;
    o[i] = f2bf(f1[k * 512 + n]);
  } else if (i < 196608) {
    int t = i - 131072;
    int n = t >> 9, k = t & 511;
    o[i] = f2bf(f2[k * 128 + n]);
  }
}

// 96-row 8-wave GEMM: wave owns ONE 16-col tile (col0 = wave*16), 6 row-tiles.
// Weight reads partitioned 1:1 across waves (R17 lesson: never duplicate).
// mfma(F1,F2): lane(l16,kg) holds D[f2row=l16][f1row=kg*4+r]; acc[6] = 24 VGPRs.
__device__ __forceinline__ void gemm96(const u16* __restrict__ A, const u16* __restrict__ WT,
                                       int ldw, f32x4 acc[6],
                                       int wave, int lane16, int kgrp) {
#pragma unroll
  for (int ks = 0; ks < 4; ++ks) {
    const int kk = ks * 32 + kgrp * 8;
    const bf16x8 b = *(const bf16x8*)(WT + (wave * 16 + lane16) * ldw + kk);
    __builtin_amdgcn_s_setprio(1);
#pragma unroll
    for (int xr = 0; xr < 6; ++xr) {
      const bf16x8 a = *(const bf16x8*)(A + (xr * 16 + lane16) * LDA + kk);
      acc[xr] = MFMA32(b, a, acc[xr]);
    }
    __builtin_amdgcn_s_setprio(0);
  }
}

__device__ __forceinline__ void store96(u16* __restrict__ dst, f32x4 acc[6],
                                        const float* __restrict__ bias,
                                        int wave, int lane16, int kgrp) {
  const int col0 = wave * 16 + kgrp * 4;
  const float4 bv = *(const float4*)(bias + col0);
#pragma unroll
  for (int xr = 0; xr < 6; ++xr) {
    uint2 o;
    o.x = pk2bf(acc[xr][0] + bv.x, acc[xr][1] + bv.y);
    o.y = pk2bf(acc[xr][2] + bv.z, acc[xr][3] + bv.w);
    *(uint2*)(dst + (xr * 16 + lane16) * LDA + col0) = o;
  }
}

__global__ __launch_bounds__(512) void mitra_main(
    const float* __restrict__ x,
    const float* __restrict__ nw1, const float* __restrict__ nb1,
    const float* __restrict__ nw2, const float* __restrict__ nb2,
    const float* __restrict__ qb,  const float* __restrict__ kb,
    const float* __restrict__ vb,  const float* __restrict__ ob,
    const float* __restrict__ f1b, const float* __restrict__ f2b,
    const u16* __restrict__ wt, float* __restrict__ out) {
  __shared__ u16 XF[NROWS * LDA];   // xf -> xf2 -> FF G ping buffer
  __shared__ u16 BA[NROWS * LDA];   // Q -> V -> H
  __shared__ u16 BB[NROWS * LDA];   // K -> O -> FF G pong buffer
  __shared__ u16 PS2[2 * NROWS * 8];   // scores/probs bf16: [h][q][k-in-slot(6, pad 8)]

  const int tid    = threadIdx.x;
  const int wave   = tid >> 6;      // 0..7
  const int lane   = tid & 63;
  const int lane16 = lane & 15;
  const int kgrp   = lane >> 4;
  const long slot0 = (long)blockIdx.x * SLOTS;

  // ---------- Phase 0: LN1(768) + LN2(128) -> XF  (wave handles 2 slots) ----------
#pragma unroll
  for (int si = 0; si < 2; ++si) {
    const int s = wave + si * 8;      // slot 0..15
    const float* xr = x + (size_t)(slot0 + s) * 768;
    const int l32 = lane & 31;
    float4 v[3];
    float sm = 0.f, sq = 0.f;
#pragma unroll
    for (int p = 0; p < 3; ++p) {
      v[p] = *(const float4*)(xr + (p * 64 + lane) * 4);
      sm += v[p].x + v[p].y + v[p].z + v[p].w;
      sq += v[p].x * v[p].x + v[p].y * v[p].y + v[p].z * v[p].z + v[p].w * v[p].w;
    }
#pragma unroll
    for (int m = 1; m < 64; m <<= 1) { sm += __shfl_xor(sm, m); sq += __shfl_xor(sq, m); }
    const float mu = sm * (1.f / 768.f);
    const float rs = rsqrtf(sq * (1.f / 768.f) - mu * mu + 1e-5f);
#pragma unroll
    for (int p = 0; p < 3; ++p) {
      const float4 w = *(const float4*)(nw1 + (p * 64 + lane) * 4);
      const float4 b = *(const float4*)(nb1 + (p * 64 + lane) * 4);
      v[p].x = (v[p].x - mu) * rs * w.x + b.x;
      v[p].y = (v[p].y - mu) * rs * w.y + b.y;
      v[p].z = (v[p].z - mu) * rs * w.z + b.z;
      v[p].w = (v[p].w - mu) * rs * w.w + b.w;
    }
    const float4 w2 = *(const float4*)(nw2 + l32 * 4);
    const float4 b2 = *(const float4*)(nb2 + l32 * 4);
#pragma unroll
    for (int p = 0; p < 3; ++p) {
      float s2 = v[p].x + v[p].y + v[p].z + v[p].w;
      float q2 = v[p].x * v[p].x + v[p].y * v[p].y + v[p].z * v[p].z + v[p].w * v[p].w;
#pragma unroll
      for (int m = 1; m < 32; m <<= 1) { s2 += __shfl_xor(s2, m); q2 += __shfl_xor(q2, m); }
      const float mu2 = s2 * (1.f / 128.f);
      const float rs2 = rsqrtf(q2 * (1.f / 128.f) - mu2 * mu2 + 1e-5f);
      const int row = s * 6 + 2 * p + (lane >> 5);
      uint2 o;
      o.x = pk2bf((v[p].x - mu2) * rs2 * w2.x + b2.x, (v[p].y - mu2) * rs2 * w2.y + b2.y);
      o.y = pk2bf((v[p].z - mu2) * rs2 * w2.z + b2.z, (v[p].w - mu2) * rs2 * w2.w + b2.w);
      *(uint2*)(XF + row * LDA + l32 * 4) = o;
    }
  }
  __syncthreads();

  // ---------- Q -> BA, K -> BB ----------
  {
    f32x4 acc[6] = {};
    gemm96(XF, wt + 0, 128, acc, wave, lane16, kgrp);
    store96(BA, acc, qb, wave, lane16, kgrp);
  }
  {
    f32x4 acc[6] = {};
    gemm96(XF, wt + 16384, 128, acc, wave, lane16, kgrp);
    store96(BB, acc, kb, wave, lane16, kgrp);
  }
  __syncthreads();

  // ---------- scores via MFMA: 28 jobs (14 near-diag tiles x 2 heads) over 8 waves ----------
  {
#pragma unroll
    for (int jl = 0; jl < 4; ++jl) {
      const int j = wave + jl * 8;
      if (j < 28) {
        const int h  = j & 1;
        const int tt = j >> 1;                 // 0..13
        int qt, kt;
        if (tt < 6) { qt = tt; kt = tt; }
        else {
          const int idx  = tt - 6;             // 0..7
          const int base = idx >> 1;           // 0..3
          const int lo   = base + (base >> 1); // 0,1,3,4
          const int dir  = idx & 1;
          qt = lo + dir; kt = lo + 1 - dir;
        }
        f32x4 acc = {};
#pragma unroll
        for (int ks = 0; ks < 2; ++ks) {
          const int kk = h * 64 + ks * 32 + kgrp * 8;
          const bf16x8 kf = *(const bf16x8*)(BB + (kt * 16 + lane16) * LDA + kk);
          const bf16x8 qf = *(const bf16x8*)(BA + (qt * 16 + lane16) * LDA + kk);
          acc = MFMA32(kf, qf, acc);
        }
        const int q    = qt * 16 + lane16;
        const int klo  = 6 * ((unsigned)q / 6u);
        u16* pq = PS2 + (h * NROWS + q) * 8;
#pragma unroll
        for (int r = 0; r < 4; ++r) {
          const int off = kt * 16 + kgrp * 4 + r - klo;
          if ((unsigned)off < 6u) pq[off] = f2bf(acc[r] * 0.125f);
        }
      }
    }
  }
  __syncthreads();

  // ---------- V -> BA (Q dead) with softmax merged (PS2-only, no hazard) ----------
  {
    f32x4 acc[6] = {};
    gemm96(XF, wt + 32768, 128, acc, wave, lane16, kgrp);
    store96(BA, acc, vb, wave, lane16, kgrp);
  }
  if (lane < 24) {
    const int h  = lane / 12;
    const int q  = wave * 12 + (lane % 12);
    u16* pr = PS2 + (h * NROWS + q) * 8;
    float e[6];
    float m = bf2f(pr[0]);
#pragma unroll
    for (int k = 1; k < 6; ++k) m = fmaxf(m, bf2f(pr[k]));
    float ssum = 0.f;
#pragma unroll
    for (int k = 0; k < 6; ++k) { e[k] = EXP2F((bf2f(pr[k]) - m) * 1.44269504f); ssum += e[k]; }
    const float inv = __builtin_amdgcn_rcpf(ssum);
#pragma unroll
    for (int k = 0; k < 6; ++k) pr[k] = f2bf(e[k] * inv);
  }
  __syncthreads();

  // ---------- O = P @ V -> BB: wave w owns rows 12w..12w+11, all 128 cols ----------
  {
    const int dseg = lane & 15;
    const int d0   = dseg * 8;
    const int h    = dseg >> 3;
    const int rgrp = lane >> 4;
#pragma unroll
    for (int p = 0; p < 3; ++p) {
      const int rl = rgrp * 3 + p;          // 0..11
      const int q  = wave * 12 + rl;
      const int sl = rl / 6;
      const u16* pr = PS2 + (h * NROWS + q) * 8;
      const u16* vbase = BA + (wave * 12 + sl * 6) * LDA + d0;
      float o0 = 0, o1 = 0, o2 = 0, o3 = 0, o4 = 0, o5 = 0, o6 = 0, o7 = 0;
#pragma unroll
      for (int k = 0; k < 6; ++k) {
        const uint4 v4 = *(const uint4*)(vbase + k * LDA);
        const float pw = bf2f(pr[k]);
        const float2 a = bf2x2(v4.x), b = bf2x2(v4.y);
        const float2 c = bf2x2(v4.z), d = bf2x2(v4.w);
        o0 = fmaf(pw, a.x, o0); o1 = fmaf(pw, a.y, o1);
        o2 = fmaf(pw, b.x, o2); o3 = fmaf(pw, b.y, o3);
        o4 = fmaf(pw, c.x, o4); o5 = fmaf(pw, c.y, o5);
        o6 = fmaf(pw, d.x, o6); o7 = fmaf(pw, d.y, o7);
      }
      uint4 o;
      o.x = pk2bf(o0, o1); o.y = pk2bf(o2, o3);
      o.z = pk2bf(o4, o5); o.w = pk2bf(o6, o7);
      *(uint4*)(BB + q * LDA + d0) = o;
    }
  }
  __syncthreads();

  // ---------- att_out = O @ ow + ob ; xf2 = xf + att_out -> XF ----------
  {
    f32x4 acc[6] = {};
    gemm96(BB, wt + 49152, 128, acc, wave, lane16, kgrp);
    const int col0 = wave * 16 + kgrp * 4;
    const float4 bv = *(const float4*)(ob + col0);
#pragma unroll
    for (int xr = 0; xr < 6; ++xr) {
      u16* px = XF + (xr * 16 + lane16) * LDA + col0;
      const uint2 cur = *(const uint2*)px;
      const float2 lo = bf2x2(cur.x), hi = bf2x2(cur.y);
      uint2 o;
      o.x = pk2bf(lo.x + acc[xr][0] + bv.x, lo.y + acc[xr][1] + bv.y);
      o.y = pk2bf(hi.x + acc[xr][2] + bv.z, hi.y + acc[xr][3] + bv.w);
      *(uint2*)px = o;
    }
  }
  __syncthreads();

  // ---------- H = LN2(xf2) -> BA (V dead): 16 groups x 6 rows ----------
  {
    const int g = tid >> 5, l32 = tid & 31;
    const float4 w2 = *(const float4*)(nw2 + l32 * 4);
    const float4 b2 = *(const float4*)(nb2 + l32 * 4);
#pragma unroll
    for (int i = 0; i < 6; ++i) {
      const int row = g * 6 + i;
      const uint2 hv = *(const uint2*)(XF + row * LDA + l32 * 4);
      const float2 lo = bf2x2(hv.x), hi = bf2x2(hv.y);
      float s2 = lo.x + lo.y + hi.x + hi.y;
      float q2 = lo.x * lo.x + lo.y * lo.y + hi.x * hi.x + hi.y * hi.y;
#pragma unroll
      for (int m = 1; m < 32; m <<= 1) { s2 += __shfl_xor(s2, m); q2 += __shfl_xor(q2, m); }
      const float mu2 = s2 * (1.f / 128.f);
      const float rs2 = rsqrtf(q2 * (1.f / 128.f) - mu2 * mu2 + 1e-5f);
      uint2 o;
      o.x = pk2bf((lo.x - mu2) * rs2 * w2.x + b2.x, (lo.y - mu2) * rs2 * w2.y + b2.y);
      o.y = pk2bf((hi.x - mu2) * rs2 * w2.z + b2.z, (hi.y - mu2) * rs2 * w2.w + b2.w);
      *(uint2*)(BA + row * LDA + l32 * 4) = o;
    }
  }

  // ---------- preload acc2 with xf2 (frees XF as an FF G buffer) ----------
  f32x4 acc2[6];
  {
    const int col0 = wave * 16 + kgrp * 4;
#pragma unroll
    for (int xr = 0; xr < 6; ++xr) {
      const uint2 t2 = *(const uint2*)(XF + (xr * 16 + lane16) * LDA + col0);
      const float2 lo = bf2x2(t2.x), hi = bf2x2(t2.y);
      acc2[xr][0] = lo.x; acc2[xr][1] = lo.y;
      acc2[xr][2] = hi.x; acc2[xr][3] = hi.y;
    }
  }
  __syncthreads();

  // ---------- FF with G ping-pong {BB, XF}: one barrier per t ----------
  {
    f32x4 g[6] = {};
    gemm96(BA, wt + 65536, 128, g, wave, lane16, kgrp);
    const int col0 = wave * 16 + kgrp * 4;
    const float4 bv = *(const float4*)(f1b + col0);
#pragma unroll
    for (int xr = 0; xr < 6; ++xr) {
      uint2 o;
      o.x = pk2bf(gelu_f(g[xr][0] + bv.x), gelu_f(g[xr][1] + bv.y));
      o.y = pk2bf(gelu_f(g[xr][2] + bv.z), gelu_f(g[xr][3] + bv.w));
      *(uint2*)(BB + (xr * 16 + lane16) * LDA + col0) = o;
    }
  }
  __syncthreads();
#pragma unroll
  for (int t = 1; t < 4; ++t) {
    u16* const Gprev = (t & 1) ? BB : XF;
    u16* const Gcur  = (t & 1) ? XF : BB;
    gemm96(Gprev, wt + 131072 + (t - 1) * 128, 512, acc2, wave, lane16, kgrp);
    f32x4 g[6] = {};
    gemm96(BA, wt + 65536 + t * 16384, 128, g, wave, lane16, kgrp);
    const int col0 = wave * 16 + kgrp * 4;
    const float4 bv = *(const float4*)(f1b + t * 128 + col0);
#pragma unroll
    for (int xr = 0; xr < 6; ++xr) {
      uint2 o;
      o.x = pk2bf(gelu_f(g[xr][0] + bv.x), gelu_f(g[xr][1] + bv.y));
      o.y = pk2bf(gelu_f(g[xr][2] + bv.z), gelu_f(g[xr][3] + bv.w));
      *(uint2*)(Gcur + (xr * 16 + lane16) * LDA + col0) = o;
    }
    __syncthreads();
  }
  gemm96(XF, wt + 131072 + 3 * 128, 512, acc2, wave, lane16, kgrp);

  // ---------- out = x + (xf2 + ff_out) + ff2b  (acc2 already holds xf2) ----------
  {
    const int col0 = wave * 16 + kgrp * 4;
    const float4 fb = *(const float4*)(f2b + col0);
#pragma unroll
    for (int xr = 0; xr < 6; ++xr) {
      const int row  = xr * 16 + lane16;
      const int slot = row / 6, ch = row % 6;
      const size_t gi = (size_t)(slot0 + slot) * 768 + ch * 128 + col0;
      const float4 xv = *(const float4*)(x + gi);
      float4 o;
      o.x = xv.x + acc2[xr][0] + fb.x;
      o.y = xv.y + acc2[xr][1] + fb.y;
      o.z = xv.z + acc2[xr][2] + fb.z;
      o.w = xv.w + acc2[xr][3] + fb.w;
      *(float4*)(out + gi) = o;
    }
  }
}

extern "C" void kernel_launch(void* const* d_in, const int* in_sizes, int n_in,
                              void* d_out, int out_size, void* d_ws, size_t ws_size,
                              hipStream_t stream) {
  const float* x   = (const float*)d_in[0];
  const float* nw1 = (const float*)d_in[1];
  const float* nb1 = (const float*)d_in[2];
  const float* nw2 = (const float*)d_in[3];
  const float* nb2 = (const float*)d_in[4];
  const float* qw  = (const float*)d_in[5];
  const float* qb  = (const float*)d_in[6];
  const float* kw  = (const float*)d_in[7];
  const float* kb  = (const float*)d_in[8];
  const float* vw  = (const float*)d_in[9];
  const float* vb  = (const float*)d_in[10];
  const float* ow  = (const float*)d_in[11];
  const float* ob  = (const float*)d_in[12];
  const float* f1w = (const float*)d_in[13];
  const float* f1b = (const float*)d_in[14];
  const float* f2w = (const float*)d_in[15];
  const float* f2b = (const float*)d_in[16];
  u16* wt = (u16*)d_ws;   // 196608 u16 = 384 KB

  convert_w<<<768, 256, 0, stream>>>(qw, kw, vw, ow, f1w, f2w, wt);

  const int M = in_sizes[0] / 768;   // 32768 slots
  mitra_main<<<M / SLOTS, 512, 0, stream>>>(x, nw1, nb1, nw2, nb2,
                                            qb, kb, vb, ob, f1b, f2b,
                                            wt, (float*)d_out);
}